// Round 10
// baseline (26.160 us; speedup 1.0000x reference)
//
#include <hip/hip_runtime.h>

// LabelSmoothing: weighted soft-target CE, C=3, prefix-valid mask, per-sample
// mean, batch sum. Two-kernel structure.
// Round-10: persistent-ish blocks. 2048 blocks x 4 chunks (chunk = 1024 rows).
// Block (b, sp0) handles sample b at sp = sp0 + {0,4,8,12} -- a stratified
// set, so per-block work variance <= 1 chunk. All 4 row-0 probes are issued
// together (independent loads, one HBM latency for 4 chunks, bulk-k overlaps
// probe-k+1), and the block reduction + psum write is amortized 4x.
// Masked compute stays free: zero-label rows contribute 0 loss / 0 count.

#define NB      512
#define NS      16384
#define NSPLIT  16
#define RPB     (NS / NSPLIT)   // 1024 rows per chunk
#define NTH     256
#define NPER    4               // chunks per block
#define NBLK    (NB * NSPLIT / NPER)   // 2048 blocks

__device__ __forceinline__ float row_loss(float xa, float xb, float xc,
                                          int la, int lb, int lc) {
    const float w0 = 1.23954983922f, w1 = 5.3172413793f, w2 = 192.75f;
    float m   = fmaxf(fmaxf(xa, xb), xc);
    float lse = m + __logf(__expf(xa - m) + __expf(xb - m) + __expf(xc - m));
    return w0 * (float)la * (lse - xa)
         + w1 * (float)lb * (lse - xb)
         + w2 * (float)lc * (lse - xc);
}

__global__ __launch_bounds__(NTH) void ls_partial(
    const float* __restrict__ x, const int* __restrict__ lab,
    float* __restrict__ psum, int* __restrict__ pcnt)
{
    const int blk = blockIdx.x;           // 0 .. NBLK-1
    const int b   = blk & (NB - 1);       // sample
    const int sp0 = blk >> 9;             // 0..3: chunk stratum

    const int*   lr[NPER];
    const float* xr[NPER];
    int probe[NPER];

    // issue all 4 probes together: independent loads, one latency
#pragma unroll
    for (int k = 0; k < NPER; ++k) {
        const int sp = sp0 + (k << 2);    // sp0 + {0,4,8,12}
        const long long base = ((long long)b * NS + (long long)sp * RPB) * 3;
        lr[k] = lab + base;
        xr[k] = x + base;
        probe[k] = lr[k][0] | lr[k][1] | lr[k][2];
    }

    float sumA = 0.0f, sumB = 0.0f;
    int   cnt  = 0;

#pragma unroll
    for (int k = 0; k < NPER; ++k) {
        if (probe[k] == 0) continue;      // chunk fully past the prefix

        // one unconditional bulk round: 6 x 16B hoisted loads per thread
        const int4*   lp0 = (const int4*)lr[k] + (size_t)threadIdx.x * 3;
        const float4* xp0 = (const float4*)xr[k] + (size_t)threadIdx.x * 3;

        int4   a0 = lp0[0], a1 = lp0[1], a2 = lp0[2];
        float4 u0 = xp0[0], u1 = xp0[1], u2 = xp0[2];

        sumA += row_loss(u0.x, u0.y, u0.z, a0.x, a0.y, a0.z);
        cnt  += ((a0.x | a0.y | a0.z) != 0);
        sumB += row_loss(u0.w, u1.x, u1.y, a0.w, a1.x, a1.y);
        cnt  += ((a0.w | a1.x | a1.y) != 0);
        sumA += row_loss(u1.z, u1.w, u2.x, a1.z, a1.w, a2.x);
        cnt  += ((a1.z | a1.w | a2.x) != 0);
        sumB += row_loss(u2.y, u2.z, u2.w, a2.y, a2.z, a2.w);
        cnt  += ((a2.y | a2.z | a2.w) != 0);
    }

    // wave (64-lane) + block reduction of sum and cnt
    float sum = sumA + sumB;
#pragma unroll
    for (int off = 32; off > 0; off >>= 1) {
        sum += __shfl_down(sum, off);
        cnt += __shfl_down(cnt, off);
    }
    __shared__ float ssum[NTH / 64];
    __shared__ int   scnt[NTH / 64];
    const int lane = threadIdx.x & 63;
    const int wid  = threadIdx.x >> 6;
    if (lane == 0) { ssum[wid] = sum; scnt[wid] = cnt; }
    __syncthreads();
    if (threadIdx.x == 0) {
        float ts = 0.0f; int tc = 0;
#pragma unroll
        for (int i = 0; i < NTH / 64; ++i) { ts += ssum[i]; tc += scnt[i]; }
        psum[blk] = ts;
        pcnt[blk] = tc;
    }
}

__global__ __launch_bounds__(NB) void ls_final(
    const float* __restrict__ psum, const int* __restrict__ pcnt,
    float* __restrict__ out)
{
    const int b = threadIdx.x;            // one thread per sample
    float s = 0.0f; int c = 0;
#pragma unroll
    for (int j = 0; j < NPER; ++j) {      // partials at b + j*512 (sp0 = j)
        s += psum[b + j * NB];
        c += pcnt[b + j * NB];
    }
    float per = s / (float)c;             // c >= 1 (lengths are 1..S)

#pragma unroll
    for (int off = 32; off > 0; off >>= 1) per += __shfl_down(per, off);
    __shared__ float sh[NB / 64];
    const int lane = threadIdx.x & 63;
    const int wid  = threadIdx.x >> 6;
    if (lane == 0) sh[wid] = per;
    __syncthreads();
    if (threadIdx.x == 0) {
        float t = 0.0f;
#pragma unroll
        for (int i = 0; i < NB / 64; ++i) t += sh[i];
        out[0] = t;
    }
}

extern "C" void kernel_launch(void* const* d_in, const int* in_sizes, int n_in,
                              void* d_out, int out_size, void* d_ws, size_t ws_size,
                              hipStream_t stream)
{
    const float* x   = (const float*)d_in[0];
    const int*   lab = (const int*)d_in[1];

    float* psum = (float*)d_ws;
    int*   pcnt = (int*)((char*)d_ws + (size_t)NBLK * sizeof(float));

    ls_partial<<<NBLK, NTH, 0, stream>>>(x, lab, psum, pcnt);
    ls_final<<<1, NB, 0, stream>>>(psum, pcnt, (float*)d_out);
}